// Round 3
// baseline (105.158 us; speedup 1.0000x reference)
//
#include <hip/hip_runtime.h>

// FastGaussianModel: values[m] = sum_n exp(-0.5 * sum_d (p[m,d]-q[n,d])^2 * iv[n,d]) * w[n]
// quad' = c' + a.p + b.p^2 per gaussian, K = -0.5*log2(e) folded into coeffs.
//
// Round 3: launch-structure experiment. Rounds 1-2 had identical totals with
// completely different data paths -> suspect dispatch overhead + atomic fan-in,
// not pipes. Now: 2 dispatches (no memset, no atomics), one thread owns one
// point and sums all N gaussians; 64-thread blocks spread 782 blocks over all
// 256 CUs. Coef layout: pair-interleaved AoS, loop-uniform addresses
// (scalar-load friendly), 7 v_pk_fma_f32 + 2 v_exp_f32 per 2 gaussians.

typedef float v2f __attribute__((ext_vector_type(2)));

constexpr int BLOCK = 64;   // one wave per block; 782 blocks ~ 3/CU

// --- prep: per-PAIR packed coefficients: 16 floats per gaussian pair ---
// layout per pair i: [a0.xy, a1.xy, a2.xy, b0.xy, b1.xy, b2.xy, c.xy, w.xy]
__global__ void fgm_prep(const float* __restrict__ positions,
                         const float* __restrict__ log_scales,
                         const float* __restrict__ intensities,
                         float* __restrict__ coef, int N, int Npairs) {
    int i = blockIdx.x * blockDim.x + threadIdx.x;   // pair index
    if (i >= Npairs) return;
    float v[2][8];
    for (int h = 0; h < 2; ++h) {
        int n = 2 * i + h;
        float a0=0.f,a1=0.f,a2=0.f,b0=0.f,b1=0.f,b2=0.f,c=0.f,w=0.f;
        if (n < N) {
            const float K = -0.7213475204444817f;  // -0.5 * log2(e)
            float q0 = positions[3*n+0], q1 = positions[3*n+1], q2 = positions[3*n+2];
            float iv0 = 1.0f / (__expf(2.0f*log_scales[3*n+0]) + 1e-6f);
            float iv1 = 1.0f / (__expf(2.0f*log_scales[3*n+1]) + 1e-6f);
            float iv2 = 1.0f / (__expf(2.0f*log_scales[3*n+2]) + 1e-6f);
            a0 = K * (-2.f*iv0*q0);  b0 = K * iv0;
            a1 = K * (-2.f*iv1*q1);  b1 = K * iv1;
            a2 = K * (-2.f*iv2*q2);  b2 = K * iv2;
            c  = K * (iv0*q0*q0 + iv1*q1*q1 + iv2*q2*q2);
            w  = intensities[n];
        }
        v[h][0]=a0; v[h][1]=a1; v[h][2]=a2; v[h][3]=b0;
        v[h][4]=b1; v[h][5]=b2; v[h][6]=c;  v[h][7]=w;
    }
    float4* out = (float4*)(coef + (size_t)i * 16);
    out[0] = make_float4(v[0][0], v[1][0], v[0][1], v[1][1]);  // a0.xy a1.xy
    out[1] = make_float4(v[0][2], v[1][2], v[0][3], v[1][3]);  // a2.xy b0.xy
    out[2] = make_float4(v[0][4], v[1][4], v[0][5], v[1][5]);  // b1.xy b2.xy
    out[3] = make_float4(v[0][6], v[1][6], v[0][7], v[1][7]);  // c.xy  w.xy
}

// --- main: one thread per point, sum over ALL gaussians, direct store ---
__global__ __launch_bounds__(BLOCK) void fgm_main(const float* __restrict__ points,
                                                  const float* __restrict__ coef,
                                                  float* __restrict__ out,
                                                  int M, int Npairs) {
    int m = blockIdx.x * BLOCK + threadIdx.x;
    float px = 0.f, py = 0.f, pz = 0.f;
    if (m < M) {
        px = points[3*m+0];
        py = points[3*m+1];
        pz = points[3*m+2];
    }
    v2f vpx  = {px, px},       vpy  = {py, py},       vpz  = {pz, pz};
    v2f vpx2 = {px*px, px*px}, vpy2 = {py*py, py*py}, vpz2 = {pz*pz, pz*pz};

    const v2f* cp = (const v2f*)coef;   // 8 v2f per pair, loop-uniform address
    v2f acc = {0.f, 0.f};
    #pragma unroll 4
    for (int i = 0; i < Npairs; ++i) {
        v2f A0 = cp[8*i+0], A1 = cp[8*i+1], A2 = cp[8*i+2], B0 = cp[8*i+3];
        v2f B1 = cp[8*i+4], B2 = cp[8*i+5], C  = cp[8*i+6], W  = cp[8*i+7];
        v2f t = __builtin_elementwise_fma(A0, vpx,  C);
        t = __builtin_elementwise_fma(A1, vpy,  t);
        t = __builtin_elementwise_fma(A2, vpz,  t);
        t = __builtin_elementwise_fma(B0, vpx2, t);
        t = __builtin_elementwise_fma(B1, vpy2, t);
        t = __builtin_elementwise_fma(B2, vpz2, t);
        v2f g;
        g.x = __builtin_amdgcn_exp2f(t.x);
        g.y = __builtin_amdgcn_exp2f(t.y);
        acc = __builtin_elementwise_fma(g, W, acc);
    }
    if (m < M) out[m] = acc.x + acc.y;
}

extern "C" void kernel_launch(void* const* d_in, const int* in_sizes, int n_in,
                              void* d_out, int out_size, void* d_ws, size_t ws_size,
                              hipStream_t stream) {
    const float* points      = (const float*)d_in[0];
    const float* positions   = (const float*)d_in[1];
    const float* log_scales  = (const float*)d_in[2];
    const float* intensities = (const float*)d_in[3];
    int M = in_sizes[0] / 3;
    int N = in_sizes[3];

    int Npairs = (N + 1) / 2;
    float* coef = (float*)d_ws;  // Npairs * 16 floats

    fgm_prep<<<(Npairs + 255) / 256, 256, 0, stream>>>(positions, log_scales,
                                                       intensities, coef, N, Npairs);

    fgm_main<<<(M + BLOCK - 1) / BLOCK, BLOCK, 0, stream>>>(points, coef,
                                                            (float*)d_out, M, Npairs);
}

// Round 4
// 77.515 us; speedup vs baseline: 1.3566x; 1.3566x over previous
//
#include <hip/hip_runtime.h>

// FastGaussianModel: values[m] = sum_n exp(-0.5 * sum_d (p[m,d]-q[n,d])^2 * iv[n,d]) * w[n]
// quad' = c' + a.p + b.p^2 per gaussian, K = -0.5*log2(e) folded into coeffs.
//
// Round 4: scalar-path fix. R3 analysis: 32 KB pair-table thrashes the ~16 KB
// scalar K$ (every iter = K$ miss ~200 cyc) AND only 0.76 waves/SIMD -> no
// overlap. Now: 4-wave blocks share 64 points (lane<->point); each wave sweeps
// a K$-sized 8 KB quarter of the gaussian table via uniform s_load_dwordx16
// stream; LDS used ONLY for the once-per-block 4-way fan-in (broadcast reads
// in the hot loop are banned: LDS return BW is per-lane bytes). 3128 waves
// (~3/SIMD) give cross-wave latency overlap. No atomics, no memset.

typedef float v2f __attribute__((ext_vector_type(2)));

constexpr int BLOCK = 256;            // 4 waves
constexpr int PTS_PER_BLOCK = 64;     // lane <-> point

// --- prep: per-PAIR packed coefficients: 16 floats per gaussian pair ---
// layout per pair i: [a0.xy, a1.xy, a2.xy, b0.xy, b1.xy, b2.xy, c.xy, w.xy]
__global__ void fgm_prep(const float* __restrict__ positions,
                         const float* __restrict__ log_scales,
                         const float* __restrict__ intensities,
                         float* __restrict__ coef, int N, int NpairsPad) {
    int i = blockIdx.x * blockDim.x + threadIdx.x;   // pair index
    if (i >= NpairsPad) return;
    float v[2][8];
    for (int h = 0; h < 2; ++h) {
        int n = 2 * i + h;
        float a0=0.f,a1=0.f,a2=0.f,b0=0.f,b1=0.f,b2=0.f,c=0.f,w=0.f;
        if (n < N) {
            const float K = -0.7213475204444817f;  // -0.5 * log2(e)
            float q0 = positions[3*n+0], q1 = positions[3*n+1], q2 = positions[3*n+2];
            float iv0 = 1.0f / (__expf(2.0f*log_scales[3*n+0]) + 1e-6f);
            float iv1 = 1.0f / (__expf(2.0f*log_scales[3*n+1]) + 1e-6f);
            float iv2 = 1.0f / (__expf(2.0f*log_scales[3*n+2]) + 1e-6f);
            a0 = K * (-2.f*iv0*q0);  b0 = K * iv0;
            a1 = K * (-2.f*iv1*q1);  b1 = K * iv1;
            a2 = K * (-2.f*iv2*q2);  b2 = K * iv2;
            c  = K * (iv0*q0*q0 + iv1*q1*q1 + iv2*q2*q2);
            w  = intensities[n];
        }
        v[h][0]=a0; v[h][1]=a1; v[h][2]=a2; v[h][3]=b0;
        v[h][4]=b1; v[h][5]=b2; v[h][6]=c;  v[h][7]=w;
    }
    float4* out = (float4*)(coef + (size_t)i * 16);
    out[0] = make_float4(v[0][0], v[1][0], v[0][1], v[1][1]);  // a0.xy a1.xy
    out[1] = make_float4(v[0][2], v[1][2], v[0][3], v[1][3]);  // a2.xy b0.xy
    out[2] = make_float4(v[0][4], v[1][4], v[0][5], v[1][5]);  // b1.xy b2.xy
    out[3] = make_float4(v[0][6], v[1][6], v[0][7], v[1][7]);  // c.xy  w.xy
}

// --- main: 4 waves/block, lane<->point, wave sweeps its gaussian quarter ---
__global__ __launch_bounds__(BLOCK, 3) void fgm_main(const float* __restrict__ points,
                                                     const float* __restrict__ coef,
                                                     float* __restrict__ out,
                                                     int M, int pairsPerWave,
                                                     int NpairsPad) {
    __shared__ float red[4][PTS_PER_BLOCK];

    int lane = threadIdx.x & 63;
    // scalarize wave id so coef addresses are provably wave-uniform -> s_load
    int wave = __builtin_amdgcn_readfirstlane(threadIdx.x >> 6);

    int m = blockIdx.x * PTS_PER_BLOCK + lane;
    float px = 0.f, py = 0.f, pz = 0.f;
    if (m < M) {
        px = points[3*m+0];
        py = points[3*m+1];
        pz = points[3*m+2];
    }
    v2f vpx  = {px, px},       vpy  = {py, py},       vpz  = {pz, pz};
    v2f vpx2 = {px*px, px*px}, vpy2 = {py*py, py*py}, vpz2 = {pz*pz, pz*pz};

    int pairBase = wave * pairsPerWave;
    int pairEnd  = pairBase + pairsPerWave;
    if (pairEnd > NpairsPad) pairEnd = NpairsPad;

    const v2f* cp = (const v2f*)coef;   // 8 v2f per pair, loop-uniform address
    v2f acc = {0.f, 0.f};
    #pragma unroll 4
    for (int i = pairBase; i < pairEnd; ++i) {
        v2f A0 = cp[8*i+0], A1 = cp[8*i+1], A2 = cp[8*i+2], B0 = cp[8*i+3];
        v2f B1 = cp[8*i+4], B2 = cp[8*i+5], C  = cp[8*i+6], W  = cp[8*i+7];
        v2f t = __builtin_elementwise_fma(A0, vpx,  C);
        t = __builtin_elementwise_fma(A1, vpy,  t);
        t = __builtin_elementwise_fma(A2, vpz,  t);
        t = __builtin_elementwise_fma(B0, vpx2, t);
        t = __builtin_elementwise_fma(B1, vpy2, t);
        t = __builtin_elementwise_fma(B2, vpz2, t);
        v2f g;
        g.x = __builtin_amdgcn_exp2f(t.x);
        g.y = __builtin_amdgcn_exp2f(t.y);
        acc = __builtin_elementwise_fma(g, W, acc);
    }

    red[wave][lane] = acc.x + acc.y;
    __syncthreads();
    if (wave == 0 && m < M) {
        out[m] = (red[0][lane] + red[1][lane]) + (red[2][lane] + red[3][lane]);
    }
}

extern "C" void kernel_launch(void* const* d_in, const int* in_sizes, int n_in,
                              void* d_out, int out_size, void* d_ws, size_t ws_size,
                              hipStream_t stream) {
    const float* points      = (const float*)d_in[0];
    const float* positions   = (const float*)d_in[1];
    const float* log_scales  = (const float*)d_in[2];
    const float* intensities = (const float*)d_in[3];
    int M = in_sizes[0] / 3;
    int N = in_sizes[3];

    int Npairs       = (N + 1) / 2;
    int pairsPerWave = (Npairs + 3) / 4;
    int NpairsPad    = pairsPerWave * 4;   // prep zero-pads (w=0) the tail

    float* coef = (float*)d_ws;  // NpairsPad * 16 floats

    fgm_prep<<<(NpairsPad + 255) / 256, 256, 0, stream>>>(positions, log_scales,
                                                          intensities, coef,
                                                          N, NpairsPad);

    int blocks = (M + PTS_PER_BLOCK - 1) / PTS_PER_BLOCK;
    fgm_main<<<blocks, BLOCK, 0, stream>>>(points, coef, (float*)d_out,
                                           M, pairsPerWave, NpairsPad);
}